// Round 14
// baseline (345.041 us; speedup 1.0000x reference)
//
#include <hip/hip_runtime.h>

typedef _Float16 half8 __attribute__((ext_vector_type(8)));
typedef _Float16 half4 __attribute__((ext_vector_type(4)));
typedef float f32x4 __attribute__((ext_vector_type(4)));
typedef unsigned short u16;
typedef unsigned char u8;
typedef unsigned int u32;

constexpr int F_IN = 256;
constexpr int H    = 128;
constexpr int C    = 16;
constexpr int KITER = 10;

constexpr int RANGE = 32768;  // nodes per histogram range (8192 packed-u8 u32 words = 32 KB)
constexpr int PCH   = 128;    // edge chunks

// ---------------- packed-u8 LDS histogram (no global atomics) ----------------

__global__ __launch_bounds__(256) void hist_k(const int* __restrict__ idx,
                                              u8* __restrict__ partial,
                                              int N, int E, int R, int chunk) {
    __shared__ unsigned int cnt[RANGE / 4];  // 32 KB
    const int p  = blockIdx.x / R;
    const int r  = blockIdx.x % R;
    const int lo = r * RANGE;
    const int hi = min(lo + RANGE, N);
    const int t  = threadIdx.x;
    for (int i = t; i < RANGE / 4; i += 256) cnt[i] = 0;
    __syncthreads();
    const int e0 = p * chunk, e1 = min(e0 + chunk, E);
    for (int e = e0 + t; e < e1; e += 256) {
        int d = idx[e];
        if (d >= lo && d < hi) {
            int dl = d - lo;
            atomicAdd(&cnt[dl >> 2], 1u << ((dl & 3) << 3));
        }
    }
    __syncthreads();
    for (int i = lo + t; i < hi; i += 256) {
        int il = i - lo;
        partial[(size_t)p * N + i] = (u8)(cnt[il >> 2] >> ((il & 3) << 3));
    }
}

// dst-hist that ALSO records each edge's rank within (chunk p, node d).
__global__ __launch_bounds__(256) void hist_rank_k(const int* __restrict__ idx,
                                                   u8* __restrict__ partial,
                                                   u8* __restrict__ rank8,
                                                   int N, int E, int R, int chunk) {
    __shared__ unsigned int cnt[RANGE / 4];  // 32 KB
    const int p  = blockIdx.x / R;
    const int r  = blockIdx.x % R;
    const int lo = r * RANGE;
    const int hi = min(lo + RANGE, N);
    const int t  = threadIdx.x;
    for (int i = t; i < RANGE / 4; i += 256) cnt[i] = 0;
    __syncthreads();
    const int e0 = p * chunk, e1 = min(e0 + chunk, E);
    for (int e = e0 + t; e < e1; e += 256) {
        int d = idx[e];
        if (d >= lo && d < hi) {
            int dl    = d - lo;
            int shift = (dl & 3) << 3;
            unsigned int old = atomicAdd(&cnt[dl >> 2], 1u << shift);
            rank8[e] = (u8)((old >> shift) & 0xffu);
        }
    }
    __syncthreads();
    for (int i = lo + t; i < hi; i += 256) {
        int il = i - lo;
        partial[(size_t)p * N + i] = (u8)(cnt[il >> 2] >> ((il & 3) << 3));
    }
}

__global__ __launch_bounds__(256) void colsum_k(const u8* __restrict__ partial,
                                                int* __restrict__ deg, int N) {
    int i = blockIdx.x * 256 + threadIdx.x;
    if (i < N) {
        int s = 0;
#pragma unroll 8
        for (int p = 0; p < PCH; ++p) s += partial[(size_t)p * N + i];
        deg[i] = s;
    }
}

// exclusive prefix along p over dst-partial; emits ns, nd; fused block-local scan.
__global__ __launch_bounds__(256) void colprefix_norm_scan_k(u8* __restrict__ partial,
                                                             const int* __restrict__ dego,
                                                             float* __restrict__ ns,
                                                             float* __restrict__ nd,
                                                             int* __restrict__ off,
                                                             int* __restrict__ bsum, int N) {
    __shared__ int s[256];
    int t = threadIdx.x, i = blockIdx.x * 256 + t;
    int run = 0;
    if (i < N) {
        for (int p = 0; p < PCH; ++p) {
            size_t q = (size_t)p * N + i;
            int v = partial[q];
            partial[q] = (u8)run;
            run += v;
        }
        int a = dego[i];
        ns[i] = (a > 0) ? rsqrtf((float)a) : 0.0f;
        nd[i] = (run > 0) ? rsqrtf((float)run) : 0.0f;
    }
    s[t] = run;  // 0 for i >= N
    __syncthreads();
    for (int dd = 1; dd < 256; dd <<= 1) {
        int x = (t >= dd) ? s[t - dd] : 0;
        __syncthreads();
        s[t] += x;
        __syncthreads();
    }
    if (i < N) off[i] = s[t] - run;
    if (t == 255) bsum[blockIdx.x] = s[255];
}

__global__ __launch_bounds__(512) void scan2(int* __restrict__ bsum, int nb) {
    __shared__ int s[512];
    int t = threadIdx.x;
    int v = (t < nb) ? bsum[t] : 0;
    s[t] = v;
    __syncthreads();
    for (int dd = 1; dd < 512; dd <<= 1) {
        int x = (t >= dd) ? s[t - dd] : 0;
        __syncthreads();
        s[t] += x;
        __syncthreads();
    }
    if (t < nb) bsum[t] = s[t] - v;
}

__global__ __launch_bounds__(256) void scan3(int* __restrict__ off, const int* __restrict__ bsum,
                                             int N) {
    int i = blockIdx.x * 256 + threadIdx.x;
    if (i < N) off[i] += bsum[blockIdx.x];
}

// ---------------- single-pass CSR scatter (streaming; ranks precomputed) ----------------

__global__ __launch_bounds__(256) void scatter_pass(const int* __restrict__ src,
                                                    const int* __restrict__ dst,
                                                    const int* __restrict__ off,
                                                    const u8* __restrict__ pprefix,
                                                    const u8* __restrict__ rank8,
                                                    u32* __restrict__ epack,
                                                    int N, int E, int chunk) {
    int e = blockIdx.x * 256 + threadIdx.x;
    if (e < E) {
        int d = dst[e];
        int p = e / chunk;
        int pos = off[d] + (int)pprefix[(size_t)p * N + d] + (int)rank8[e];
        epack[pos] = (u32)src[e];
    }
}

// ---------------- fused weight packing to MFMA fragment order ----------------
// B[(ks*NT + nt)*64 + l][j] = (f16) W[ks*32 + (l>>4)*8 + j][nt*16 + (l&15)]

__device__ inline void pack_one(const float* __restrict__ W, half8* __restrict__ out,
                                int tid, int NT, int Ncols) {
    int l  = tid & 63;
    int q  = tid >> 6;
    int nt = q % NT;
    int ks = q / NT;
    int col = nt * 16 + (l & 15);
    int kb  = ks * 32 + ((l >> 4) * 8);
    half8 h;
#pragma unroll
    for (int j = 0; j < 8; ++j) h[j] = (_Float16)W[(kb + j) * Ncols + col];
    out[tid] = h;
}

__global__ __launch_bounds__(256) void wpack_all(const float* __restrict__ W0,
                                                 const float* __restrict__ W1,
                                                 const float* __restrict__ W2,
                                                 half8* __restrict__ B0,
                                                 half8* __restrict__ B1,
                                                 half8* __restrict__ B2) {
    int tid = blockIdx.x * 256 + threadIdx.x;
    if (tid < 4096)      pack_one(W0, B0, tid, 8, 128);
    else if (tid < 6144) pack_one(W1, B1, tid - 4096, 8, 128);
    else if (tid < 6400) pack_one(W2, B2, tid - 6144, 1, 16);
}

// ---------------- MLP: low-VGPR (<=64) for full co-residency ----------------
// (256,8) forces VGPR<=64 -> 8 waves/SIMD capacity; the whole grid (6.1
// waves/SIMD) is co-resident in ONE batch, so all latency chains overlap.
// Feat loaded in two 8-load chunks; layer-0 split into two nt-halves to
// keep live-set <= ~60 regs. No barriers; H buffer wave-private.

__global__ __launch_bounds__(256, 8) void mlp_lo(
    const float* __restrict__ feat,
    const half8* __restrict__ B0, const float* __restrict__ b0,
    const half8* __restrict__ B1, const float* __restrict__ b1,
    const half8* __restrict__ B2, const float* __restrict__ b2,
    const float* __restrict__ ns,
    float* __restrict__ h0out, _Float16* __restrict__ g0out, int N)
{
    __shared__ __align__(16) char lds[4 * 4096];
    const int t  = threadIdx.x;
    const int l  = t & 63;
    const int w  = t >> 6;
    const int cl = l & 15;
    const int qk = l >> 4;
    char* swp = lds + w * 4096;  // wave-private H buffer

    const int rowg = blockIdx.x * 64 + w * 16 + cl;
    const int rowc = (rowg < N) ? rowg : (N - 1);
    const float* ap = feat + (size_t)rowc * F_IN + qk * 8;

    half8 a0[8];
    // ---- feat chunk 1 (ks 0..3): 8 loads in flight ----
    {
        float4 f[8];
#pragma unroll
        for (int ks = 0; ks < 4; ++ks) {
            f[2 * ks]     = *reinterpret_cast<const float4*>(ap + ks * 32);
            f[2 * ks + 1] = *reinterpret_cast<const float4*>(ap + ks * 32 + 4);
        }
        __builtin_amdgcn_sched_barrier(0);
#pragma unroll
        for (int ks = 0; ks < 4; ++ks) {
            half8 h;
            h[0] = (_Float16)f[2 * ks].x;     h[1] = (_Float16)f[2 * ks].y;
            h[2] = (_Float16)f[2 * ks].z;     h[3] = (_Float16)f[2 * ks].w;
            h[4] = (_Float16)f[2 * ks + 1].x; h[5] = (_Float16)f[2 * ks + 1].y;
            h[6] = (_Float16)f[2 * ks + 1].z; h[7] = (_Float16)f[2 * ks + 1].w;
            a0[ks] = h;
        }
    }
    // ---- feat chunk 2 (ks 4..7) ----
    {
        float4 f[8];
#pragma unroll
        for (int ks = 4; ks < 8; ++ks) {
            f[2 * (ks - 4)]     = *reinterpret_cast<const float4*>(ap + ks * 32);
            f[2 * (ks - 4) + 1] = *reinterpret_cast<const float4*>(ap + ks * 32 + 4);
        }
        __builtin_amdgcn_sched_barrier(0);
#pragma unroll
        for (int ks = 4; ks < 8; ++ks) {
            half8 h;
            h[0] = (_Float16)f[2 * (ks - 4)].x;     h[1] = (_Float16)f[2 * (ks - 4)].y;
            h[2] = (_Float16)f[2 * (ks - 4)].z;     h[3] = (_Float16)f[2 * (ks - 4)].w;
            h[4] = (_Float16)f[2 * (ks - 4) + 1].x; h[5] = (_Float16)f[2 * (ks - 4) + 1].y;
            h[6] = (_Float16)f[2 * (ks - 4) + 1].z; h[7] = (_Float16)f[2 * (ks - 4) + 1].w;
            a0[ks] = h;
        }
    }

    // ---- layer 0: two nt-halves (acc live-set 16 regs each) ----
#pragma unroll
    for (int hf = 0; hf < 2; ++hf) {
        f32x4 acc[4];
#pragma unroll
        for (int nt = 0; nt < 4; ++nt) acc[nt] = (f32x4){0.f, 0.f, 0.f, 0.f};
#pragma unroll
        for (int ks = 0; ks < 8; ++ks)
#pragma unroll
            for (int nt = 0; nt < 4; ++nt)
                acc[nt] = __builtin_amdgcn_mfma_f32_16x16x32_f16(
                    a0[ks], B0[(ks * 8 + hf * 4 + nt) * 64 + l], acc[nt], 0, 0, 0);
#pragma unroll
        for (int nt = 0; nt < 4; ++nt) {
            int col = hf * 64 + nt * 16 + cl;
            float bb = b0[col];
#pragma unroll
            for (int r = 0; r < 4; ++r) {
                int orow = qk * 4 + r;
                int byte = orow * 256 + ((col * 2) ^ ((orow & 7) << 4));
                *reinterpret_cast<_Float16*>(swp + byte) = (_Float16)fmaxf(acc[nt][r] + bb, 0.0f);
            }
        }
    }

    // ---- layer 1: read all H1 frags to regs, then overwrite with H2 ----
    half8 a1[4];
#pragma unroll
    for (int ks = 0; ks < 4; ++ks) {
        int byte = cl * 256 + (((qk * 8 + ks * 32) * 2) ^ ((cl & 7) << 4));
        a1[ks] = *reinterpret_cast<const half8*>(swp + byte);
    }
    f32x4 acc1[8];
#pragma unroll
    for (int nt = 0; nt < 8; ++nt) acc1[nt] = (f32x4){0.f, 0.f, 0.f, 0.f};
#pragma unroll
    for (int ks = 0; ks < 4; ++ks)
#pragma unroll
        for (int nt = 0; nt < 8; ++nt)
            acc1[nt] = __builtin_amdgcn_mfma_f32_16x16x32_f16(a1[ks], B1[(ks * 8 + nt) * 64 + l],
                                                              acc1[nt], 0, 0, 0);
#pragma unroll
    for (int nt = 0; nt < 8; ++nt) {
        float bb = b1[nt * 16 + cl];
#pragma unroll
        for (int r = 0; r < 4; ++r) {
            int orow = qk * 4 + r;
            int byte = orow * 256 + (((nt * 16 + cl) * 2) ^ ((orow & 7) << 4));
            *reinterpret_cast<_Float16*>(swp + byte) = (_Float16)fmaxf(acc1[nt][r] + bb, 0.0f);
        }
    }

    // ---- layer 2 ----
    f32x4 acc2 = (f32x4){0.f, 0.f, 0.f, 0.f};
#pragma unroll
    for (int ks = 0; ks < 4; ++ks) {
        int byte = cl * 256 + (((qk * 8 + ks * 32) * 2) ^ ((cl & 7) << 4));
        half8 a2 = *reinterpret_cast<const half8*>(swp + byte);
        acc2 = __builtin_amdgcn_mfma_f32_16x16x32_f16(a2, B2[ks * 64 + l], acc2, 0, 0, 0);
    }
    float bb2 = b2[cl];
#pragma unroll
    for (int r = 0; r < 4; ++r) {
        int orow = qk * 4 + r;
        int node = blockIdx.x * 64 + w * 16 + orow;
        if (node < N) {
            float hv = acc2[r] + bb2;
            h0out[(size_t)node * C + cl] = hv;
            g0out[(size_t)node * C + cl] = (_Float16)(hv * ns[node]);
        }
    }
}

// ---------------- propagation: gather of pre-scaled f16 g, unroll-8 (r12 form) ----------------

__global__ __launch_bounds__(256) void gatherg(const u32* __restrict__ ep,
                                               const int* __restrict__ off,
                                               const half4* __restrict__ g,
                                               const float4* __restrict__ h0,
                                               const float* __restrict__ ns,
                                               const float* __restrict__ nd,
                                               half4* __restrict__ gnext,
                                               float4* __restrict__ hout,
                                               int N, int E, int last) {
    int gid = blockIdx.x * 256 + threadIdx.x;
    int node = gid >> 2;
    if (node >= N) return;
    int c = gid & 3;
    int o0 = off[node];
    int o1 = (node + 1 < N) ? off[node + 1] : E;
    float k  = 0.9f * nd[node];
    float sc = ns[node];
    float4 hv = h0[gid];
    float4 aA = {0.f, 0.f, 0.f, 0.f};
    float4 aB = {0.f, 0.f, 0.f, 0.f};
    float4 aC = {0.f, 0.f, 0.f, 0.f};
    float4 aD = {0.f, 0.f, 0.f, 0.f};
    int o = o0;
    for (; o + 8 <= o1; o += 8) {
        int s0 = (int)ep[o];     int s1 = (int)ep[o + 1];
        int s2 = (int)ep[o + 2]; int s3 = (int)ep[o + 3];
        int s4 = (int)ep[o + 4]; int s5 = (int)ep[o + 5];
        int s6 = (int)ep[o + 6]; int s7 = (int)ep[o + 7];
        half4 x0 = g[s0 * 4 + c]; half4 x1 = g[s1 * 4 + c];
        half4 x2 = g[s2 * 4 + c]; half4 x3 = g[s3 * 4 + c];
        half4 x4 = g[s4 * 4 + c]; half4 x5 = g[s5 * 4 + c];
        half4 x6 = g[s6 * 4 + c]; half4 x7 = g[s7 * 4 + c];
        aA.x += (float)x0[0]; aA.y += (float)x0[1]; aA.z += (float)x0[2]; aA.w += (float)x0[3];
        aB.x += (float)x1[0]; aB.y += (float)x1[1]; aB.z += (float)x1[2]; aB.w += (float)x1[3];
        aC.x += (float)x2[0]; aC.y += (float)x2[1]; aC.z += (float)x2[2]; aC.w += (float)x2[3];
        aD.x += (float)x3[0]; aD.y += (float)x3[1]; aD.z += (float)x3[2]; aD.w += (float)x3[3];
        aA.x += (float)x4[0]; aA.y += (float)x4[1]; aA.z += (float)x4[2]; aA.w += (float)x4[3];
        aB.x += (float)x5[0]; aB.y += (float)x5[1]; aB.z += (float)x5[2]; aB.w += (float)x5[3];
        aC.x += (float)x6[0]; aC.y += (float)x6[1]; aC.z += (float)x6[2]; aC.w += (float)x6[3];
        aD.x += (float)x7[0]; aD.y += (float)x7[1]; aD.z += (float)x7[2]; aD.w += (float)x7[3];
    }
    for (; o + 2 <= o1; o += 2) {
        int s0 = (int)ep[o];
        int s1 = (int)ep[o + 1];
        half4 x0 = g[s0 * 4 + c];
        half4 x1 = g[s1 * 4 + c];
        aA.x += (float)x0[0]; aA.y += (float)x0[1]; aA.z += (float)x0[2]; aA.w += (float)x0[3];
        aB.x += (float)x1[0]; aB.y += (float)x1[1]; aB.z += (float)x1[2]; aB.w += (float)x1[3];
    }
    if (o < o1) {
        int s0 = (int)ep[o];
        half4 x0 = g[s0 * 4 + c];
        aA.x += (float)x0[0]; aA.y += (float)x0[1]; aA.z += (float)x0[2]; aA.w += (float)x0[3];
    }
    aA.x += aB.x + aC.x + aD.x;
    aA.y += aB.y + aC.y + aD.y;
    aA.z += aB.z + aC.z + aD.z;
    aA.w += aB.w + aC.w + aD.w;
    float4 res;
    res.x = fmaf(k, aA.x, 0.1f * hv.x);
    res.y = fmaf(k, aA.y, 0.1f * hv.y);
    res.z = fmaf(k, aA.z, 0.1f * hv.z);
    res.w = fmaf(k, aA.w, 0.1f * hv.w);
    if (last) {
        hout[gid] = res;
    } else {
        half4 gv;
        gv[0] = (_Float16)(res.x * sc);
        gv[1] = (_Float16)(res.y * sc);
        gv[2] = (_Float16)(res.z * sc);
        gv[3] = (_Float16)(res.w * sc);
        gnext[gid] = gv;
    }
}

// ---------------- launch ----------------

extern "C" void kernel_launch(void* const* d_in, const int* in_sizes, int n_in,
                              void* d_out, int out_size, void* d_ws, size_t ws_size,
                              hipStream_t stream) {
    const float* feat = (const float*)d_in[0];
    const float* W0   = (const float*)d_in[1];
    const float* b0   = (const float*)d_in[2];
    const float* W1   = (const float*)d_in[3];
    const float* b1   = (const float*)d_in[4];
    const float* W2   = (const float*)d_in[5];
    const float* b2   = (const float*)d_in[6];
    const int*   src  = (const int*)d_in[7];
    const int*   dst  = (const int*)d_in[8];

    const int N = in_sizes[0] / F_IN;        // 100000
    const int E = in_sizes[7];               // 1600000
    const int NB = (N + 255) / 256;          // 391
    const int R  = (N + RANGE - 1) / RANGE;  // 4
    const int chunk = (E + PCH - 1) / PCH;   // 12500

    char* base = (char*)d_ws;
    // Region A: partial histogram (u8, 12.8 MB), dead after scatter_pass.
    u8* part = (u8*)base;
    // Region B aliases A (+slack): h/g buffers first written AFTER scatter_pass.
    float*    h0 = (float*)base;                                  // 6.4 MB
    _Float16* g0 = (_Float16*)(base + (size_t)N * C * 4);         // 3.2 MB
    _Float16* ga = (_Float16*)(base + (size_t)N * C * 6);         // 3.2 MB
    _Float16* gb = (_Float16*)(base + (size_t)N * C * 8);         // 3.2 MB
    char* ws = base + (size_t)N * C * 10;    // = 16 MB mark (> 12.8 MB partial)
    int*   dego = (int*)ws;   ws += (size_t)N * 4;
    float* ns   = (float*)ws; ws += (size_t)N * 4;
    float* nd   = (float*)ws; ws += (size_t)N * 4;
    int*   off  = (int*)ws;   ws += (size_t)N * 4;
    int*   bsum = (int*)ws;   ws += 512 * 4;
    u8*    rank8 = (u8*)ws;   ws += (size_t)E;
    ws = (char*)(((size_t)ws + 15) & ~(size_t)15);
    u32*   epack  = (u32*)ws; ws += (size_t)E * 4;
    half8* B0 = (half8*)ws;   ws += 4096 * 16;
    half8* B1 = (half8*)ws;   ws += 2048 * 16;
    half8* B2 = (half8*)ws;   ws += 256 * 16;

    // degrees via packed-u8 LDS histograms (+rank recording on dst pass)
    hist_k<<<PCH * R, 256, 0, stream>>>(src, part, N, E, R, chunk);
    colsum_k<<<NB, 256, 0, stream>>>(part, dego, N);
    hist_rank_k<<<PCH * R, 256, 0, stream>>>(dst, part, rank8, N, E, R, chunk);
    colprefix_norm_scan_k<<<NB, 256, 0, stream>>>(part, dego, ns, nd, off, bsum, N);

    // CSR offsets + single-pass streaming scatter
    scan2<<<1, 512, 0, stream>>>(bsum, NB);
    scan3<<<NB, 256, 0, stream>>>(off, bsum, N);
    scatter_pass<<<(E + 255) / 256, 256, 0, stream>>>(src, dst, off, part, rank8, epack, N, E, chunk);

    // MLP
    wpack_all<<<25, 256, 0, stream>>>(W0, W1, W2, B0, B1, B2);
    mlp_lo<<<(N + 63) / 64, 256, 0, stream>>>(feat, B0, b0, B1, b1, B2, b2, ns, h0, g0, N);

    // propagation
    const _Float16* curg = g0;
    for (int it = 0; it < KITER; ++it) {
        int last = (it == KITER - 1);
        _Float16* nxtg = (it & 1) ? gb : ga;
        gatherg<<<(N * 4 + 255) / 256, 256, 0, stream>>>(epack, off, (const half4*)curg,
                                                         (const float4*)h0, ns, nd,
                                                         (half4*)nxtg, (float4*)d_out, N, E, last);
        curg = nxtg;
    }
}

// Round 15
// 323.791 us; speedup vs baseline: 1.0656x; 1.0656x over previous
//
#include <hip/hip_runtime.h>

typedef _Float16 half8 __attribute__((ext_vector_type(8)));
typedef _Float16 half4 __attribute__((ext_vector_type(4)));
typedef float f32x4 __attribute__((ext_vector_type(4)));
typedef unsigned short u16;
typedef unsigned char u8;
typedef unsigned int u32;

constexpr int F_IN = 256;
constexpr int H    = 128;
constexpr int C    = 16;
constexpr int KITER = 10;

constexpr int RANGE = 32768;  // nodes per histogram range (8192 packed-u8 u32 words = 32 KB)
constexpr int PCH   = 128;    // edge chunks

// ---------------- packed-u8 LDS histogram (no global atomics) ----------------
// 4 counters per u32 word; per-(chunk,node) counts <= ~10 << 255.

__global__ __launch_bounds__(256) void hist_k(const int* __restrict__ idx,
                                              u8* __restrict__ partial,
                                              int N, int E, int R, int chunk) {
    __shared__ unsigned int cnt[RANGE / 4];  // 32 KB
    const int p  = blockIdx.x / R;
    const int r  = blockIdx.x % R;
    const int lo = r * RANGE;
    const int hi = min(lo + RANGE, N);
    const int t  = threadIdx.x;
    for (int i = t; i < RANGE / 4; i += 256) cnt[i] = 0;
    __syncthreads();
    const int e0 = p * chunk, e1 = min(e0 + chunk, E);
    for (int e = e0 + t; e < e1; e += 256) {
        int d = idx[e];
        if (d >= lo && d < hi) {
            int dl = d - lo;
            atomicAdd(&cnt[dl >> 2], 1u << ((dl & 3) << 3));
        }
    }
    __syncthreads();
    // flush as packed u32 words (4 nodes each)
    const int nw = (hi - lo) >> 2;
    u8* prow = partial + (size_t)p * N + lo;
    for (int k = t; k < nw; k += 256)
        *reinterpret_cast<u32*>(prow + k * 4) = cnt[k];
    for (int i = lo + nw * 4 + t; i < hi; i += 256) {  // scalar tail (unused when (hi-lo)%4==0)
        int il = i - lo;
        partial[(size_t)p * N + i] = (u8)(cnt[il >> 2] >> ((il & 3) << 3));
    }
}

// dst-hist that ALSO records each edge's rank within (chunk p, node d).
__global__ __launch_bounds__(256) void hist_rank_k(const int* __restrict__ idx,
                                                   u8* __restrict__ partial,
                                                   u8* __restrict__ rank8,
                                                   int N, int E, int R, int chunk) {
    __shared__ unsigned int cnt[RANGE / 4];  // 32 KB
    const int p  = blockIdx.x / R;
    const int r  = blockIdx.x % R;
    const int lo = r * RANGE;
    const int hi = min(lo + RANGE, N);
    const int t  = threadIdx.x;
    for (int i = t; i < RANGE / 4; i += 256) cnt[i] = 0;
    __syncthreads();
    const int e0 = p * chunk, e1 = min(e0 + chunk, E);
    for (int e = e0 + t; e < e1; e += 256) {
        int d = idx[e];
        if (d >= lo && d < hi) {
            int dl    = d - lo;
            int shift = (dl & 3) << 3;
            unsigned int old = atomicAdd(&cnt[dl >> 2], 1u << shift);
            rank8[e] = (u8)((old >> shift) & 0xffu);
        }
    }
    __syncthreads();
    const int nw = (hi - lo) >> 2;
    u8* prow = partial + (size_t)p * N + lo;
    for (int k = t; k < nw; k += 256)
        *reinterpret_cast<u32*>(prow + k * 4) = cnt[k];
    for (int i = lo + nw * 4 + t; i < hi; i += 256) {
        int il = i - lo;
        partial[(size_t)p * N + i] = (u8)(cnt[il >> 2] >> ((il & 3) << 3));
    }
}

// ---------------- colsum: 1 thread = 4 nodes (uchar4 loads, int4 store) ----------------

__global__ __launch_bounds__(256) void colsum4_k(const u8* __restrict__ partial,
                                                 int* __restrict__ deg, int NG, int N) {
    int q = blockIdx.x * 256 + threadIdx.x;
    if (q >= NG) return;
    int i0 = q * 4;
    if (i0 + 4 <= N) {
        int s0 = 0, s1 = 0, s2 = 0, s3 = 0;
#pragma unroll 8
        for (int p = 0; p < PCH; ++p) {
            uchar4 v = *reinterpret_cast<const uchar4*>(partial + (size_t)p * N + i0);
            s0 += v.x; s1 += v.y; s2 += v.z; s3 += v.w;
        }
        *reinterpret_cast<int4*>(deg + i0) = make_int4(s0, s1, s2, s3);
    } else {
        for (int i = i0; i < N; ++i) {
            int s = 0;
            for (int p = 0; p < PCH; ++p) s += partial[(size_t)p * N + i];
            deg[i] = s;
        }
    }
}

// ---------------- colprefix + norms + fused block scan: 1 thread = 4 nodes ----------------

__global__ __launch_bounds__(256) void colprefix_norm_scan4_k(u8* __restrict__ partial,
                                                              const int* __restrict__ dego,
                                                              float* __restrict__ ns,
                                                              float* __restrict__ nd,
                                                              int* __restrict__ off,
                                                              int* __restrict__ bsum,
                                                              int NG, int N) {
    __shared__ int s[256];
    int t = threadIdx.x, q = blockIdx.x * 256 + t;
    int r0 = 0, r1 = 0, r2 = 0, r3 = 0;
    int i0 = q * 4;
    bool full = (q < NG) && (i0 + 4 <= N);
    if (full) {
        for (int p = 0; p < PCH; ++p) {
            size_t base = (size_t)p * N + i0;
            uchar4 v = *reinterpret_cast<const uchar4*>(partial + base);
            uchar4 w; w.x = (u8)r0; w.y = (u8)r1; w.z = (u8)r2; w.w = (u8)r3;
            *reinterpret_cast<uchar4*>(partial + base) = w;
            r0 += v.x; r1 += v.y; r2 += v.z; r3 += v.w;
        }
        int4 dg = *reinterpret_cast<const int4*>(dego + i0);
        float4 nsv, ndv;
        nsv.x = (dg.x > 0) ? rsqrtf((float)dg.x) : 0.0f;
        nsv.y = (dg.y > 0) ? rsqrtf((float)dg.y) : 0.0f;
        nsv.z = (dg.z > 0) ? rsqrtf((float)dg.z) : 0.0f;
        nsv.w = (dg.w > 0) ? rsqrtf((float)dg.w) : 0.0f;
        ndv.x = (r0 > 0) ? rsqrtf((float)r0) : 0.0f;
        ndv.y = (r1 > 0) ? rsqrtf((float)r1) : 0.0f;
        ndv.z = (r2 > 0) ? rsqrtf((float)r2) : 0.0f;
        ndv.w = (r3 > 0) ? rsqrtf((float)r3) : 0.0f;
        *reinterpret_cast<float4*>(ns + i0) = nsv;
        *reinterpret_cast<float4*>(nd + i0) = ndv;
    } else if (q < NG) {
        // scalar tail group
        int rr[4] = {0, 0, 0, 0};
        int nn = N - i0;
        for (int p = 0; p < PCH; ++p) {
            for (int j = 0; j < nn; ++j) {
                size_t qq = (size_t)p * N + i0 + j;
                int v = partial[qq];
                partial[qq] = (u8)rr[j];
                rr[j] += v;
            }
        }
        for (int j = 0; j < nn; ++j) {
            int a = dego[i0 + j];
            ns[i0 + j] = (a > 0) ? rsqrtf((float)a) : 0.0f;
            nd[i0 + j] = (rr[j] > 0) ? rsqrtf((float)rr[j]) : 0.0f;
        }
        r0 = rr[0]; r1 = rr[1]; r2 = rr[2]; r3 = rr[3];
    }
    int tot = r0 + r1 + r2 + r3;
    s[t] = (q < NG) ? tot : 0;
    __syncthreads();
    for (int dd = 1; dd < 256; dd <<= 1) {
        int x = (t >= dd) ? s[t - dd] : 0;
        __syncthreads();
        s[t] += x;
        __syncthreads();
    }
    if (q < NG) {
        int ex = s[t] - tot;  // exclusive base for this 4-node group
        if (i0 + 4 <= N) {
            int4 o;
            o.x = ex; o.y = ex + r0; o.z = ex + r0 + r1; o.w = ex + r0 + r1 + r2;
            *reinterpret_cast<int4*>(off + i0) = o;
        } else {
            int rr[4] = {r0, r1, r2, r3};
            int run = ex;
            for (int j = 0; j < N - i0; ++j) { off[i0 + j] = run; run += rr[j]; }
        }
    }
    if (t == 255) bsum[blockIdx.x] = s[255];
}

__global__ __launch_bounds__(512) void scan2(int* __restrict__ bsum, int nb) {
    __shared__ int s[512];
    int t = threadIdx.x;
    int v = (t < nb) ? bsum[t] : 0;
    s[t] = v;
    __syncthreads();
    for (int dd = 1; dd < 512; dd <<= 1) {
        int x = (t >= dd) ? s[t - dd] : 0;
        __syncthreads();
        s[t] += x;
        __syncthreads();
    }
    if (t < nb) bsum[t] = s[t] - v;
}

// matches colprefix4's 1024-node-per-block mapping; int4 update
__global__ __launch_bounds__(256) void scan3_4(int* __restrict__ off, const int* __restrict__ bsum,
                                               int NG, int N) {
    int q = blockIdx.x * 256 + threadIdx.x;
    if (q >= NG) return;
    int b = bsum[blockIdx.x];
    int i0 = q * 4;
    if (i0 + 4 <= N) {
        int4 o = *reinterpret_cast<const int4*>(off + i0);
        o.x += b; o.y += b; o.z += b; o.w += b;
        *reinterpret_cast<int4*>(off + i0) = o;
    } else {
        for (int j = 0; j < N - i0; ++j) off[i0 + j] += b;
    }
}

// ---------------- single-pass CSR scatter (streaming; ranks precomputed) ----------------

__global__ __launch_bounds__(256) void scatter_pass(const int* __restrict__ src,
                                                    const int* __restrict__ dst,
                                                    const int* __restrict__ off,
                                                    const u8* __restrict__ pprefix,
                                                    const u8* __restrict__ rank8,
                                                    u32* __restrict__ epack,
                                                    int N, int E, int chunk) {
    int e = blockIdx.x * 256 + threadIdx.x;
    if (e < E) {
        int d = dst[e];
        int p = e / chunk;
        int pos = off[d] + (int)pprefix[(size_t)p * N + d] + (int)rank8[e];
        epack[pos] = (u32)src[e];
    }
}

// ---------------- fused weight packing to MFMA fragment order ----------------
// B[(ks*NT + nt)*64 + l][j] = (f16) W[ks*32 + (l>>4)*8 + j][nt*16 + (l&15)]

__device__ inline void pack_one(const float* __restrict__ W, half8* __restrict__ out,
                                int tid, int NT, int Ncols) {
    int l  = tid & 63;
    int q  = tid >> 6;
    int nt = q % NT;
    int ks = q / NT;
    int col = nt * 16 + (l & 15);
    int kb  = ks * 32 + ((l >> 4) * 8);
    half8 h;
#pragma unroll
    for (int j = 0; j < 8; ++j) h[j] = (_Float16)W[(kb + j) * Ncols + col];
    out[tid] = h;
}

__global__ __launch_bounds__(256) void wpack_all(const float* __restrict__ W0,
                                                 const float* __restrict__ W1,
                                                 const float* __restrict__ W2,
                                                 half8* __restrict__ B0,
                                                 half8* __restrict__ B1,
                                                 half8* __restrict__ B2) {
    int tid = blockIdx.x * 256 + threadIdx.x;
    if (tid < 4096)      pack_one(W0, B0, tid, 8, 128);
    else if (tid < 6144) pack_one(W1, B1, tid - 4096, 8, 128);
    else if (tid < 6400) pack_one(W2, B2, tid - 6144, 1, 16);
}

// ---------------- MLP: direct-load A, no barriers (r9/r12 best: 59 us) ----------------

__global__ __launch_bounds__(256) void mlp_direct(
    const float* __restrict__ feat,
    const half8* __restrict__ B0, const float* __restrict__ b0,
    const half8* __restrict__ B1, const float* __restrict__ b1,
    const half8* __restrict__ B2, const float* __restrict__ b2,
    const float* __restrict__ ns,
    float* __restrict__ h0out, _Float16* __restrict__ g0out, int N)
{
    __shared__ __align__(16) char lds[4 * 4096];
    const int t  = threadIdx.x;
    const int l  = t & 63;
    const int w  = t >> 6;
    const int cl = l & 15;
    const int qk = l >> 4;
    char* swp = lds + w * 4096;  // wave-private H buffer

    const int rowg = blockIdx.x * 64 + w * 16 + cl;
    const int rowc = (rowg < N) ? rowg : (N - 1);

    // ---- phase 1: issue ALL 16 independent feat loads ----
    const float* ap = feat + (size_t)rowc * F_IN + qk * 8;
    float4 f[16];
#pragma unroll
    for (int i = 0; i < 16; ++i)
        f[i] = *reinterpret_cast<const float4*>(ap + (i >> 1) * 32 + (i & 1) * 4);
    __builtin_amdgcn_sched_barrier(0);  // loads must not sink past this point

    // ---- phase 2: convert to f16 A fragments ----
    half8 a0[8];
#pragma unroll
    for (int ks = 0; ks < 8; ++ks) {
        half8 h;
        h[0] = (_Float16)f[2 * ks].x;     h[1] = (_Float16)f[2 * ks].y;
        h[2] = (_Float16)f[2 * ks].z;     h[3] = (_Float16)f[2 * ks].w;
        h[4] = (_Float16)f[2 * ks + 1].x; h[5] = (_Float16)f[2 * ks + 1].y;
        h[6] = (_Float16)f[2 * ks + 1].z; h[7] = (_Float16)f[2 * ks + 1].w;
        a0[ks] = h;
    }

    // ---- layer 0 ----
    f32x4 acc0[8];
#pragma unroll
    for (int nt = 0; nt < 8; ++nt) acc0[nt] = (f32x4){0.f, 0.f, 0.f, 0.f};
#pragma unroll
    for (int ks = 0; ks < 8; ++ks)
#pragma unroll
        for (int nt = 0; nt < 8; ++nt)
            acc0[nt] = __builtin_amdgcn_mfma_f32_16x16x32_f16(a0[ks], B0[(ks * 8 + nt) * 64 + l],
                                                              acc0[nt], 0, 0, 0);
#pragma unroll
    for (int nt = 0; nt < 8; ++nt) {
        float bb = b0[nt * 16 + cl];
#pragma unroll
        for (int r = 0; r < 4; ++r) {
            int orow = qk * 4 + r;
            int byte = orow * 256 + (((nt * 16 + cl) * 2) ^ ((orow & 7) << 4));
            *reinterpret_cast<_Float16*>(swp + byte) = (_Float16)fmaxf(acc0[nt][r] + bb, 0.0f);
        }
    }

    // ---- layer 1 (read all H1 frags to regs, then overwrite with H2) ----
    half8 a1[4];
#pragma unroll
    for (int ks = 0; ks < 4; ++ks) {
        int byte = cl * 256 + (((qk * 8 + ks * 32) * 2) ^ ((cl & 7) << 4));
        a1[ks] = *reinterpret_cast<const half8*>(swp + byte);
    }
    f32x4 acc1[8];
#pragma unroll
    for (int nt = 0; nt < 8; ++nt) acc1[nt] = (f32x4){0.f, 0.f, 0.f, 0.f};
#pragma unroll
    for (int ks = 0; ks < 4; ++ks)
#pragma unroll
        for (int nt = 0; nt < 8; ++nt)
            acc1[nt] = __builtin_amdgcn_mfma_f32_16x16x32_f16(a1[ks], B1[(ks * 8 + nt) * 64 + l],
                                                              acc1[nt], 0, 0, 0);
#pragma unroll
    for (int nt = 0; nt < 8; ++nt) {
        float bb = b1[nt * 16 + cl];
#pragma unroll
        for (int r = 0; r < 4; ++r) {
            int orow = qk * 4 + r;
            int byte = orow * 256 + (((nt * 16 + cl) * 2) ^ ((orow & 7) << 4));
            *reinterpret_cast<_Float16*>(swp + byte) = (_Float16)fmaxf(acc1[nt][r] + bb, 0.0f);
        }
    }

    // ---- layer 2 ----
    f32x4 acc2 = (f32x4){0.f, 0.f, 0.f, 0.f};
#pragma unroll
    for (int ks = 0; ks < 4; ++ks) {
        int byte = cl * 256 + (((qk * 8 + ks * 32) * 2) ^ ((cl & 7) << 4));
        half8 a2 = *reinterpret_cast<const half8*>(swp + byte);
        acc2 = __builtin_amdgcn_mfma_f32_16x16x32_f16(a2, B2[ks * 64 + l], acc2, 0, 0, 0);
    }
    float bb2 = b2[cl];
#pragma unroll
    for (int r = 0; r < 4; ++r) {
        int orow = qk * 4 + r;
        int node = blockIdx.x * 64 + w * 16 + orow;
        if (node < N) {
            float hv = acc2[r] + bb2;
            h0out[(size_t)node * C + cl] = hv;
            g0out[(size_t)node * C + cl] = (_Float16)(hv * ns[node]);
        }
    }
}

// ---------------- propagation: gather of pre-scaled f16 g, unroll-8 (r12 form) ----------------

__global__ __launch_bounds__(256) void gatherg(const u32* __restrict__ ep,
                                               const int* __restrict__ off,
                                               const half4* __restrict__ g,
                                               const float4* __restrict__ h0,
                                               const float* __restrict__ ns,
                                               const float* __restrict__ nd,
                                               half4* __restrict__ gnext,
                                               float4* __restrict__ hout,
                                               int N, int E, int last) {
    int gid = blockIdx.x * 256 + threadIdx.x;
    int node = gid >> 2;
    if (node >= N) return;
    int c = gid & 3;
    int o0 = off[node];
    int o1 = (node + 1 < N) ? off[node + 1] : E;
    float k  = 0.9f * nd[node];
    float sc = ns[node];
    float4 hv = h0[gid];
    float4 aA = {0.f, 0.f, 0.f, 0.f};
    float4 aB = {0.f, 0.f, 0.f, 0.f};
    float4 aC = {0.f, 0.f, 0.f, 0.f};
    float4 aD = {0.f, 0.f, 0.f, 0.f};
    int o = o0;
    for (; o + 8 <= o1; o += 8) {
        int s0 = (int)ep[o];     int s1 = (int)ep[o + 1];
        int s2 = (int)ep[o + 2]; int s3 = (int)ep[o + 3];
        int s4 = (int)ep[o + 4]; int s5 = (int)ep[o + 5];
        int s6 = (int)ep[o + 6]; int s7 = (int)ep[o + 7];
        half4 x0 = g[s0 * 4 + c]; half4 x1 = g[s1 * 4 + c];
        half4 x2 = g[s2 * 4 + c]; half4 x3 = g[s3 * 4 + c];
        half4 x4 = g[s4 * 4 + c]; half4 x5 = g[s5 * 4 + c];
        half4 x6 = g[s6 * 4 + c]; half4 x7 = g[s7 * 4 + c];
        aA.x += (float)x0[0]; aA.y += (float)x0[1]; aA.z += (float)x0[2]; aA.w += (float)x0[3];
        aB.x += (float)x1[0]; aB.y += (float)x1[1]; aB.z += (float)x1[2]; aB.w += (float)x1[3];
        aC.x += (float)x2[0]; aC.y += (float)x2[1]; aC.z += (float)x2[2]; aC.w += (float)x2[3];
        aD.x += (float)x3[0]; aD.y += (float)x3[1]; aD.z += (float)x3[2]; aD.w += (float)x3[3];
        aA.x += (float)x4[0]; aA.y += (float)x4[1]; aA.z += (float)x4[2]; aA.w += (float)x4[3];
        aB.x += (float)x5[0]; aB.y += (float)x5[1]; aB.z += (float)x5[2]; aB.w += (float)x5[3];
        aC.x += (float)x6[0]; aC.y += (float)x6[1]; aC.z += (float)x6[2]; aC.w += (float)x6[3];
        aD.x += (float)x7[0]; aD.y += (float)x7[1]; aD.z += (float)x7[2]; aD.w += (float)x7[3];
    }
    for (; o + 2 <= o1; o += 2) {
        int s0 = (int)ep[o];
        int s1 = (int)ep[o + 1];
        half4 x0 = g[s0 * 4 + c];
        half4 x1 = g[s1 * 4 + c];
        aA.x += (float)x0[0]; aA.y += (float)x0[1]; aA.z += (float)x0[2]; aA.w += (float)x0[3];
        aB.x += (float)x1[0]; aB.y += (float)x1[1]; aB.z += (float)x1[2]; aB.w += (float)x1[3];
    }
    if (o < o1) {
        int s0 = (int)ep[o];
        half4 x0 = g[s0 * 4 + c];
        aA.x += (float)x0[0]; aA.y += (float)x0[1]; aA.z += (float)x0[2]; aA.w += (float)x0[3];
    }
    aA.x += aB.x + aC.x + aD.x;
    aA.y += aB.y + aC.y + aD.y;
    aA.z += aB.z + aC.z + aD.z;
    aA.w += aB.w + aC.w + aD.w;
    float4 res;
    res.x = fmaf(k, aA.x, 0.1f * hv.x);
    res.y = fmaf(k, aA.y, 0.1f * hv.y);
    res.z = fmaf(k, aA.z, 0.1f * hv.z);
    res.w = fmaf(k, aA.w, 0.1f * hv.w);
    if (last) {
        hout[gid] = res;
    } else {
        half4 gv;
        gv[0] = (_Float16)(res.x * sc);
        gv[1] = (_Float16)(res.y * sc);
        gv[2] = (_Float16)(res.z * sc);
        gv[3] = (_Float16)(res.w * sc);
        gnext[gid] = gv;
    }
}

// ---------------- launch ----------------

extern "C" void kernel_launch(void* const* d_in, const int* in_sizes, int n_in,
                              void* d_out, int out_size, void* d_ws, size_t ws_size,
                              hipStream_t stream) {
    const float* feat = (const float*)d_in[0];
    const float* W0   = (const float*)d_in[1];
    const float* b0   = (const float*)d_in[2];
    const float* W1   = (const float*)d_in[3];
    const float* b1   = (const float*)d_in[4];
    const float* W2   = (const float*)d_in[5];
    const float* b2   = (const float*)d_in[6];
    const int*   src  = (const int*)d_in[7];
    const int*   dst  = (const int*)d_in[8];

    const int N = in_sizes[0] / F_IN;        // 100000
    const int E = in_sizes[7];               // 1600000
    const int R  = (N + RANGE - 1) / RANGE;  // 4
    const int chunk = (E + PCH - 1) / PCH;   // 12500
    const int NG = (N + 3) / 4;              // 4-node groups
    const int NBG = (NG + 255) / 256;        // 98 blocks

    char* base = (char*)d_ws;
    // Region A: partial histogram (u8, 12.8 MB), dead after scatter_pass.
    u8* part = (u8*)base;
    // Region B aliases A (+slack): h/g buffers first written AFTER scatter_pass.
    float*    h0 = (float*)base;                                  // 6.4 MB
    _Float16* g0 = (_Float16*)(base + (size_t)N * C * 4);         // 3.2 MB
    _Float16* ga = (_Float16*)(base + (size_t)N * C * 6);         // 3.2 MB
    _Float16* gb = (_Float16*)(base + (size_t)N * C * 8);         // 3.2 MB
    char* ws = base + (size_t)N * C * 10;    // = 16 MB mark (> 12.8 MB partial)
    int*   dego = (int*)ws;   ws += (size_t)N * 4;
    float* ns   = (float*)ws; ws += (size_t)N * 4;
    float* nd   = (float*)ws; ws += (size_t)N * 4;
    int*   off  = (int*)ws;   ws += (size_t)N * 4;
    int*   bsum = (int*)ws;   ws += 512 * 4;
    u8*    rank8 = (u8*)ws;   ws += (size_t)E;
    ws = (char*)(((size_t)ws + 15) & ~(size_t)15);
    u32*   epack  = (u32*)ws; ws += (size_t)E * 4;
    half8* B0 = (half8*)ws;   ws += 4096 * 16;
    half8* B1 = (half8*)ws;   ws += 2048 * 16;
    half8* B2 = (half8*)ws;   ws += 256 * 16;

    // degrees via packed-u8 LDS histograms (+rank recording on dst pass)
    hist_k<<<PCH * R, 256, 0, stream>>>(src, part, N, E, R, chunk);
    colsum4_k<<<NBG, 256, 0, stream>>>(part, dego, NG, N);
    hist_rank_k<<<PCH * R, 256, 0, stream>>>(dst, part, rank8, N, E, R, chunk);
    colprefix_norm_scan4_k<<<NBG, 256, 0, stream>>>(part, dego, ns, nd, off, bsum, NG, N);

    // CSR offsets + single-pass streaming scatter
    scan2<<<1, 512, 0, stream>>>(bsum, NBG);
    scan3_4<<<NBG, 256, 0, stream>>>(off, bsum, NG, N);
    scatter_pass<<<(E + 255) / 256, 256, 0, stream>>>(src, dst, off, part, rank8, epack, N, E, chunk);

    // MLP
    wpack_all<<<25, 256, 0, stream>>>(W0, W1, W2, B0, B1, B2);
    mlp_direct<<<(N + 63) / 64, 256, 0, stream>>>(feat, B0, b0, B1, b1, B2, b2, ns, h0, g0, N);

    // propagation
    const _Float16* curg = g0;
    for (int it = 0; it < KITER; ++it) {
        int last = (it == KITER - 1);
        _Float16* nxtg = (it & 1) ? gb : ga;
        gatherg<<<(N * 4 + 255) / 256, 256, 0, stream>>>(epack, off, (const half4*)curg,
                                                         (const float4*)h0, ns, nd,
                                                         (half4*)nxtg, (float4*)d_out, N, E, last);
        curg = nxtg;
    }
}